// Round 7
// baseline (274.176 us; speedup 1.0000x reference)
//
#include <hip/hip_runtime.h>
#include <hip/hip_bf16.h>
#include <math.h>

// ---------------------------------------------------------------------------
// MultiHeadAttention: x[4,2048,1024] -> causal MHA (16 heads, d=64) -> out proj
// bf16 MFMA everywhere.
// R18: R17 base (verified 231.5us) + gemm_bt rebuilt as BK=32 TRIPLE-buffer
// with counted vmcnt (T3+T4 minimal on the proven 128^2 shape):
//  - 3 x 16KB buffers (48KB LDS) -> 3 blocks/CU (R17 lesson: 64KB dbuf capped
//    occupancy at 2 blocks/CU, launch_bounds alone was null);
//  - stage tile t+2 at top of step t (~800cy cover vs ~400 before);
//  - step ends with lgkmcnt(0); vmcnt(4); s_barrier -- tile t+2's loads stay
//    in flight ACROSS the barrier (what __syncthreads forbids);
//  - frag regs halve (one K=32 slice/step) -> ~160 unified regs, 3 waves/SIMD.
// Barrier pattern = R13's correctness-proven asm-fenced s_barrier.
// attn (R17: sigma-window PV 16x16x32, setprio) and prep unchanged.
// ---------------------------------------------------------------------------

typedef __bf16  bf16x8  __attribute__((ext_vector_type(8)));
typedef __bf16  bf16x2  __attribute__((ext_vector_type(2)));
typedef float   floatx4 __attribute__((ext_vector_type(4)));
typedef short   shortx4 __attribute__((ext_vector_type(4)));

__device__ __forceinline__ unsigned short f2bf(float f) {
    __hip_bfloat16 h = __float2bfloat16(f);
    return *reinterpret_cast<unsigned short*>(&h);
}

// pack two f32 -> 2xbf16 in one dword (HW packed cvt when available)
__device__ __forceinline__ unsigned int pkbf(float a, float b) {
#if __has_builtin(__builtin_amdgcn_cvt_pk_bf16_f32)
    bf16x2 t = __builtin_amdgcn_cvt_pk_bf16_f32(a, b);
    return __builtin_bit_cast(unsigned int, t);
#else
    return (unsigned int)f2bf(a) | ((unsigned int)f2bf(b) << 16);
#endif
}
__device__ __forceinline__ ushort4 pk4(float a, float b, float c, float d) {
    union { ushort4 u; unsigned int w[2]; } u;
    u.w[0] = pkbf(a, b);
    u.w[1] = pkbf(c, d);
    return u.u;
}

// async global->LDS, 16 B per lane; LDS dest = wave-uniform base + lane*16
__device__ __forceinline__ void gll16(const unsigned short* g, unsigned short* l) {
    __builtin_amdgcn_global_load_lds(
        (const __attribute__((address_space(1))) unsigned int*)g,
        (__attribute__((address_space(3))) unsigned int*)l, 16, 0, 0);
}

// K LDS row permutation (attn): lds row j holds global k-row pi(j),
// pi(j) = 32*(j>>5) + 4*((j>>4)&1) + 8*((j&15)>>2) + (j&3).
// krho = pi^{-1}. Verified bijective: pi(krho(r)) == r.
__device__ __forceinline__ int krho(int r) {
    return (r & 0x20) | ((r & 4) << 2) | ((r & 0x18) >> 1) | (r & 3);
}

// --------------------------------------------- fused convert x + transpose W
__global__ void prep(const float* __restrict__ x, unsigned short* __restrict__ xb,
                     const float* __restrict__ Wq, const float* __restrict__ Wk,
                     const float* __restrict__ Wv, const float* __restrict__ Wo,
                     unsigned short* __restrict__ WT, unsigned short* __restrict__ WoT) {
    __shared__ float tile[32][33];
    int bid = blockIdx.x, tid = threadIdx.x;
    if (bid < 8192) {
        int i = (bid * 256 + tid) * 4;
        float4 v = *(const float4*)(x + i);
        *(ushort4*)(xb + i) = pk4(v.x, v.y, v.z, v.w);
        return;
    }
    int id = bid - 8192;
    int mat = id >> 10, rem = id & 1023;
    const float* src = (mat == 0) ? Wq : (mat == 1) ? Wk : (mat == 2) ? Wv : Wo;
    unsigned short* dst = (mat < 3) ? WT : WoT;
    int nbase = (mat < 3) ? mat * 1024 : 0;
    int kt = (rem & 31) * 32, nt = (rem >> 5) * 32;
    int tx = tid & 31, ty = tid >> 5;  // 32 x 8
    for (int j = 0; j < 32; j += 8)
        tile[ty + j][tx] = src[(kt + ty + j) * 1024 + nt + tx];
    __syncthreads();
    for (int j = 0; j < 32; j += 8) {
        int n = nt + ty + j;
        dst[(nbase + n) * 1024 + kt + tx] = f2bf(tile[tx][ty + j]);
    }
}

// ---------------------------------------------------------------- GEMM B^T
// C[M,N] = A[M,1024] @ B^T (B stored [N][1024]). 128x128 tile, BK=32.
// Triple-buffered gll16 staging, 2-ahead prefetch, counted vmcnt(4) at the
// barrier (tile t+2's loads cross it). XOR col-unit swizzle u^(row&3) on
// source AND read (involution; uniform 8 lanes per 16B bank-unit per b128).
// 48KB LDS + <=170 unified regs -> 3 blocks/CU.
// Orientation: swapped (C^T) for Q/K columns (n0<2048) and all of EPI1.
template <int EPI, int NBLK>
__global__ __launch_bounds__(256, 3) void gemm_bt(const unsigned short* __restrict__ A,
                                                  const unsigned short* __restrict__ B,
                                                  unsigned short* __restrict__ Qo,
                                                  unsigned short* __restrict__ Ko,
                                                  unsigned short* __restrict__ Vo,
                                                  const float* __restrict__ bias,
                                                  float* __restrict__ Out) {
    __shared__ __align__(16) unsigned short As[3][128 * 32];
    __shared__ __align__(16) unsigned short Bs[3][128 * 32];

    int tid = threadIdx.x;
    int lane = tid & 63, w = tid >> 6;
    int wm = w >> 1, wn = w & 1;
    int lm = lane & 15, quad = lane >> 4;
    // T1 swizzle: bid&7 -> XCD chunk; within chunk m-fastest over the 8-band.
    int bid = blockIdx.x;
    int xcd = bid & 7, ic = bid >> 3;
    int bm = xcd * 8 + (ic & 7), bn = ic >> 3;  // bn in [0, NBLK)
    int m0 = bm * 128, n0 = bn * 128;
    bool sw = (EPI == 1) || (n0 < 2048);  // block-uniform orientation

    // stage one 128x32 K-tile of A and B into buffer `buf` (4 gll16/thread)
    auto STAGE = [&](int buf, int kb) {
#pragma unroll
        for (int p = 0; p < 2; ++p) {
            int id = p * 256 + tid;                    // 0..511
            int row = id >> 2;                         // 0..127
            int cbs = ((id & 3) ^ (row & 3)) * 8;      // swizzled source unit
            int lbase = (p * 256 + w * 64) * 8;        // wave-uniform; HW adds lane*16B
            gll16(&A[(m0 + row) * 1024 + kb + cbs], &As[buf][lbase]);
            gll16(&B[(n0 + row) * 1024 + kb + cbs], &Bs[buf][lbase]);
        }
    };

    floatx4 acc[4][4] = {};

    // prologue: tiles 0,1 in flight; wait tile 0 only (4 of 8 drained)
    STAGE(0, 0);
    STAGE(1, 32);
    asm volatile("s_waitcnt vmcnt(4)" ::: "memory");
    __builtin_amdgcn_s_barrier();
    asm volatile("" ::: "memory");

    int cur = 0, stg = 2;   // read buf, stage buf (t+2)%3
#pragma unroll 1
    for (int t = 0; t < 32; ++t) {
        if (t + 2 < 32) STAGE(stg, (t + 2) * 32);  // 2-ahead; flies 2 steps

        const unsigned short* Ac = &As[cur][0];
        const unsigned short* Bc = &Bs[cur][0];
        bf16x8 af[4], bf[4];
#pragma unroll
        for (int i = 0; i < 4; ++i) {
            int pu = (quad ^ (lm & 3)) * 8;            // swizzled unit
            af[i] = *(const bf16x8*)&Ac[(wm * 64 + i * 16 + lm) * 32 + pu];
            bf[i] = *(const bf16x8*)&Bc[(wn * 64 + i * 16 + lm) * 32 + pu];
        }
        if (sw) {
#pragma unroll
            for (int mi = 0; mi < 4; ++mi)
#pragma unroll
                for (int ni = 0; ni < 4; ++ni)
                    acc[mi][ni] = __builtin_amdgcn_mfma_f32_16x16x32_bf16(bf[ni], af[mi], acc[mi][ni], 0, 0, 0);
        } else {
#pragma unroll
            for (int mi = 0; mi < 4; ++mi)
#pragma unroll
                for (int ni = 0; ni < 4; ++ni)
                    acc[mi][ni] = __builtin_amdgcn_mfma_f32_16x16x32_bf16(af[mi], bf[ni], acc[mi][ni], 0, 0, 0);
        }

        if (t < 31) {
            // ds reads of buf[cur] done (it is restaged next step) ...
            asm volatile("s_waitcnt lgkmcnt(0)" ::: "memory");
            // ... tile t+1 resident; tile t+2's 4 loads stay in flight.
            if (t < 30) { asm volatile("s_waitcnt vmcnt(4)" ::: "memory"); }
            else        { asm volatile("s_waitcnt vmcnt(0)" ::: "memory"); }
            __builtin_amdgcn_s_barrier();
            asm volatile("" ::: "memory");
        }
        if (++cur == 3) cur = 0;
        if (++stg == 3) stg = 0;
    }

    if constexpr (EPI == 0) {
        if (sw) {
            // C^T layout: lane owns seq s (col=lm) and 4 consecutive out-cols.
            bool isQ = (n0 < 1024);
            unsigned short* dst = isQ ? Qo : Ko;
            float qs = isQ ? 0.1803368801f : 1.0f;  // 1/8 * log2(e)
            for (int mi = 0; mi < 4; ++mi) {
                int s = m0 + wm * 64 + mi * 16 + lm;
                int bb = s >> 11, sl = s & 2047;
                for (int ni = 0; ni < 4; ++ni) {
                    int gcol0 = n0 + wn * 64 + ni * 16 + quad * 4;
                    int h = (gcol0 & 1023) >> 6, d0 = gcol0 & 63;
                    *(ushort4*)&dst[(((size_t)(bb * 16 + h) * 2048) + sl) * 64 + d0] =
                        pk4(acc[mi][ni][0] * qs, acc[mi][ni][1] * qs,
                            acc[mi][ni][2] * qs, acc[mi][ni][3] * qs);
                }
            }
        } else {
            // V columns, normal layout: packed along seq for V^T [bh][d][2048].
            for (int mi = 0; mi < 4; ++mi) {
                int grow0 = m0 + wm * 64 + mi * 16 + quad * 4;
                int bb = grow0 >> 11, sl = grow0 & 2047;
                for (int ni = 0; ni < 4; ++ni) {
                    int gcol = n0 + wn * 64 + ni * 16 + lm;
                    int hn = gcol & 1023;
                    int h = hn >> 6, d = hn & 63;
                    *(ushort4*)&Vo[((size_t)(bb * 16 + h) * 64 + d) * 2048 + sl] =
                        pk4(acc[mi][ni][0], acc[mi][ni][1], acc[mi][ni][2], acc[mi][ni][3]);
                }
            }
        }
    } else {
        // out-proj: C^T layout -> float4 stores + float4 bias loads
        for (int mi = 0; mi < 4; ++mi) {
            int s = m0 + wm * 64 + mi * 16 + lm;
            for (int ni = 0; ni < 4; ++ni) {
                int gcol0 = n0 + wn * 64 + ni * 16 + quad * 4;
                float4 bv = *(const float4*)&bias[gcol0];
                float4 o;
                o.x = acc[mi][ni][0] + bv.x; o.y = acc[mi][ni][1] + bv.y;
                o.z = acc[mi][ni][2] + bv.z; o.w = acc[mi][ni][3] + bv.w;
                *(float4*)&Out[(size_t)s * 1024 + gcol0] = o;
            }
        }
    }
}

// ------------------------------------------------------------- attention
// Flat grid 1024 = (qt heavy-first, 16 tiles of 128 q) x 64 bh.
// 512 thr = 8 waves x 16 q-rows. KB=64. S^T orientation: q=lm.
// K lds rows permuted by krho so S^T rows follow
// sigma_n(m)=32(n>>1)+4(n&1)+8(m>>2)+(m&3). PV: window pair (2n1,2n1+1)
// unions to the exact 16x16x32 B-frag (k=8*quad+j) and the b128 V read is
// the matching A-frag -> 8 mfma_16x16x32 per trip, conflict-free LDS.
// setprio(1) around MFMA clusters (T5).
// NO-MAX softmax; Q pre-scaled; lrow reduced once at the end.
__global__ __launch_bounds__(512) void attn(const unsigned short* __restrict__ Q,
                                            const unsigned short* __restrict__ K,
                                            const unsigned short* __restrict__ Vt,
                                            unsigned short* __restrict__ ctx) {
    constexpr int LKS = 72;
    __shared__ __align__(16) unsigned short Ks[2][64 * LKS];
    __shared__ __align__(16) unsigned short Vts[2][64 * LKS];

    int tid = threadIdx.x, lane = tid & 63, w = tid >> 6;   // w: 0..7
    int lm = lane & 15, quad = lane >> 4;
    int blk = blockIdx.x;
    int bh = blk & 63;
    int qt = 15 - (blk >> 6);   // LPT: heaviest q-tiles dispatch first
    int trips = 2 * qt + 2;
    int tmax = 2 * qt + (w >> 2);  // last trip this wave computes
    const unsigned short* Qg  = Q  + (size_t)bh * 2048 * 64;
    const unsigned short* Kg  = K  + (size_t)bh * 2048 * 64;
    const unsigned short* Vtg = Vt + (size_t)bh * 64 * 2048;

    int qrow = qt * 128 + w * 16 + lm;
    bf16x8 aq0 = *(const bf16x8*)&Qg[qrow * 64 + quad * 8];
    bf16x8 aq1 = *(const bf16x8*)&Qg[qrow * 64 + 32 + quad * 8];

    floatx4 O[4] = {};            // O^T: per dblk, lane holds d=quad*4+r, q=lm
    float lrow = 0.f;

    int r0 = tid >> 3, c0 = (tid & 7) * 8;  // 512 thr -> rows 0..63, 1 uint4 each
    int rK = krho(r0);                      // permuted K lds row

    {   // prologue: stage tile 0 into buffer 0
        uint4 k0 = *(const uint4*)&Kg[r0 * 64 + c0];
        uint4 v0 = *(const uint4*)&Vtg[r0 * 2048 + c0];
        *(uint4*)&Ks[0][rK * LKS + c0]  = k0;
        *(uint4*)&Vts[0][r0 * LKS + c0] = v0;
    }
    __syncthreads();

    for (int t = 0; t < trips; ++t) {
        int cur = t & 1, nxt = cur ^ 1;
        bool pre = (t + 1 < trips);
        uint4 pk, pv;
        if (pre) {  // issue next tile's loads NOW; they complete under compute
            int kb2 = (t + 1) * 64;
            pk = *(const uint4*)&Kg[(kb2 + r0) * 64 + c0];
            pv = *(const uint4*)&Vtg[r0 * 2048 + kb2 + c0];
        }

        if (t <= tmax) {  // wave-uniform; barriers are outside this branch
            const unsigned short* Kc = Ks[cur];
            const unsigned short* Vc = Vts[cur];

            floatx4 s[4];
            __builtin_amdgcn_s_setprio(1);
            for (int n = 0; n < 4; ++n) {
                bf16x8 a0 = *(const bf16x8*)&Kc[(n * 16 + lm) * LKS + quad * 8];
                bf16x8 a1 = *(const bf16x8*)&Kc[(n * 16 + lm) * LKS + 32 + quad * 8];
                floatx4 z = {};
                z = __builtin_amdgcn_mfma_f32_16x16x32_bf16(a0, aq0, z, 0, 0, 0);
                z = __builtin_amdgcn_mfma_f32_16x16x32_bf16(a1, aq1, z, 0, 0, 0);
                s[n] = z;
            }
            __builtin_amdgcn_s_setprio(0);

            bool diag = (t == tmax);
            if (diag) {
                int qr = (w & 3) * 16 + lm;  // q - kb on this wave's diag tile
                for (int n = 0; n < 4; ++n)
                    for (int r = 0; r < 4; ++r) {
                        int kin = (n >> 1) * 32 + (n & 1) * 4 + quad * 8 + r;
                        if (kin > qr) s[n][r] = -INFINITY;
                    }
            }
            float p[4][4], rs = 0.f;
            for (int n = 0; n < 4; ++n)
                for (int r = 0; r < 4; ++r) {
                    p[n][r] = __builtin_amdgcn_exp2f(s[n][r]);
                    rs += p[n][r];
                }
            lrow += rs;

            // P -> bf16; window pair (2n1,2n1+1) concatenates to the
            // 16x16x32 B-frag: lane holds k = 32n1 + 8*quad + j, j=0..7.
            unsigned int pw[4][2];
            for (int n = 0; n < 4; ++n) {
                pw[n][0] = pkbf(p[n][0], p[n][1]);
                pw[n][1] = pkbf(p[n][2], p[n][3]);
            }
            __builtin_amdgcn_s_setprio(1);
#pragma unroll
            for (int n1 = 0; n1 < 2; ++n1) {
                union { bf16x8 v; unsigned int wd[4]; } pu;
                pu.wd[0] = pw[2 * n1][0];     pu.wd[1] = pw[2 * n1][1];
                pu.wd[2] = pw[2 * n1 + 1][0]; pu.wd[3] = pw[2 * n1 + 1][1];
#pragma unroll
                for (int dblk = 0; dblk < 4; ++dblk) {
                    bf16x8 va = *(const bf16x8*)&Vc[(dblk * 16 + lm) * LKS + n1 * 32 + quad * 8];
                    O[dblk] = __builtin_amdgcn_mfma_f32_16x16x32_bf16(va, pu.v, O[dblk], 0, 0, 0);
                }
            }
            __builtin_amdgcn_s_setprio(0);
        }

        if (pre) {  // loads completed under compute; write into other buffer
            *(uint4*)&Ks[nxt][rK * LKS + c0]  = pk;
            *(uint4*)&Vts[nxt][r0 * LKS + c0] = pv;
        }
        __syncthreads();
    }

    // reduce lrow across the 4 lane-groups holding the same q (once)
    lrow += __shfl_xor(lrow, 16);
    lrow += __shfl_xor(lrow, 32);

    int b = bh >> 4, h = bh & 15;
    int q = qt * 128 + w * 16 + lm;
    float inv = 1.0f / lrow;
    for (int dblk = 0; dblk < 4; ++dblk) {
        *(ushort4*)&ctx[((size_t)(b * 2048 + q)) * 1024 + h * 64 + dblk * 16 + quad * 4] =
            pk4(O[dblk][0] * inv, O[dblk][1] * inv, O[dblk][2] * inv, O[dblk][3] * inv);
    }
}

// ---------------------------------------------------------------- launch
extern "C" void kernel_launch(void* const* d_in, const int* in_sizes, int n_in,
                              void* d_out, int out_size, void* d_ws, size_t ws_size,
                              hipStream_t stream) {
    const float* x   = (const float*)d_in[0];
    const float* Wq  = (const float*)d_in[1];
    const float* Wk  = (const float*)d_in[2];
    const float* Wv  = (const float*)d_in[3];
    const float* Wo  = (const float*)d_in[4];
    const float* bo  = (const float*)d_in[5];
    float* out = (float*)d_out;

    char* ws = (char*)d_ws;
    unsigned short* xb  = (unsigned short*)(ws);               // 16 MB (dead after gemm<0>)
    unsigned short* WT  = (unsigned short*)(ws + 16777216);    // 6 MB
    unsigned short* WoT = (unsigned short*)(ws + 23068672);    // 2 MB
    unsigned short* Qb  = (unsigned short*)(ws + 25165824);    // 16 MB
    unsigned short* Kb  = (unsigned short*)(ws + 41943040);    // 16 MB
    unsigned short* Vtb = (unsigned short*)(ws + 58720256);    // 16 MB (transposed)
    unsigned short* ctx = xb;                                  // alias: xb is dead

    prep<<<12288, 256, 0, stream>>>(x, xb, Wq, Wk, Wv, Wo, WT, WoT);
    gemm_bt<0, 24><<<1536, 256, 0, stream>>>(xb, WT, Qb, Kb, Vtb, nullptr, nullptr);
    attn<<<1024, 512, 0, stream>>>(Qb, Kb, Vtb, ctx);
    gemm_bt<1, 8><<<512, 256, 0, stream>>>(ctx, WoT, nullptr, nullptr, nullptr, bo, out);
}

// Round 8
// 232.968 us; speedup vs baseline: 1.1769x; 1.1769x over previous
//
#include <hip/hip_runtime.h>
#include <hip/hip_bf16.h>
#include <math.h>

// ---------------------------------------------------------------------------
// MultiHeadAttention: x[4,2048,1024] -> causal MHA (16 heads, d=64) -> out proj
// bf16 MFMA everywhere.
// R19: gemm_bt REVERTED to R16-exact (dbuf BK=64, 64.8us measured, 0 bank
// conflicts). R18's BK=32 triple-buffer regressed: 64B LDS rows made the
// lm&3 XOR alias lanes l/l+4 (6.29M conflicts) and halved MFMA-per-barrier.
// NEW: attn balanced-resident qt map. 1024 blocks = exactly 4/CU co-resident;
// CU hosts qt-groups {g,g+4,g+8,g+12}. Old qt=15-g -> per-CU trip sums
// {80,72,64,56} (15% tail). New qt(g)={15,13,11,9,8,10,12,14,7,5,3,1,0,2,4,6}
// -> every CU sums 68. Branch-free bit math (no runtime-indexed array).
// attn core (sigma-window PV 16x16x32, setprio) and prep unchanged.
// ---------------------------------------------------------------------------

typedef __bf16  bf16x8  __attribute__((ext_vector_type(8)));
typedef __bf16  bf16x2  __attribute__((ext_vector_type(2)));
typedef float   floatx4 __attribute__((ext_vector_type(4)));
typedef short   shortx4 __attribute__((ext_vector_type(4)));

__device__ __forceinline__ unsigned short f2bf(float f) {
    __hip_bfloat16 h = __float2bfloat16(f);
    return *reinterpret_cast<unsigned short*>(&h);
}

// pack two f32 -> 2xbf16 in one dword (HW packed cvt when available)
__device__ __forceinline__ unsigned int pkbf(float a, float b) {
#if __has_builtin(__builtin_amdgcn_cvt_pk_bf16_f32)
    bf16x2 t = __builtin_amdgcn_cvt_pk_bf16_f32(a, b);
    return __builtin_bit_cast(unsigned int, t);
#else
    return (unsigned int)f2bf(a) | ((unsigned int)f2bf(b) << 16);
#endif
}
__device__ __forceinline__ ushort4 pk4(float a, float b, float c, float d) {
    union { ushort4 u; unsigned int w[2]; } u;
    u.w[0] = pkbf(a, b);
    u.w[1] = pkbf(c, d);
    return u.u;
}

// async global->LDS, 16 B per lane; LDS dest = wave-uniform base + lane*16
__device__ __forceinline__ void gll16(const unsigned short* g, unsigned short* l) {
    __builtin_amdgcn_global_load_lds(
        (const __attribute__((address_space(1))) unsigned int*)g,
        (__attribute__((address_space(3))) unsigned int*)l, 16, 0, 0);
}

// K LDS row permutation (attn): lds row j holds global k-row pi(j),
// pi(j) = 32*(j>>5) + 4*((j>>4)&1) + 8*((j&15)>>2) + (j&3).
// krho = pi^{-1}. Verified bijective: pi(krho(r)) == r.
__device__ __forceinline__ int krho(int r) {
    return (r & 0x20) | ((r & 4) << 2) | ((r & 0x18) >> 1) | (r & 3);
}

// --------------------------------------------- fused convert x + transpose W
__global__ void prep(const float* __restrict__ x, unsigned short* __restrict__ xb,
                     const float* __restrict__ Wq, const float* __restrict__ Wk,
                     const float* __restrict__ Wv, const float* __restrict__ Wo,
                     unsigned short* __restrict__ WT, unsigned short* __restrict__ WoT) {
    __shared__ float tile[32][33];
    int bid = blockIdx.x, tid = threadIdx.x;
    if (bid < 8192) {
        int i = (bid * 256 + tid) * 4;
        float4 v = *(const float4*)(x + i);
        *(ushort4*)(xb + i) = pk4(v.x, v.y, v.z, v.w);
        return;
    }
    int id = bid - 8192;
    int mat = id >> 10, rem = id & 1023;
    const float* src = (mat == 0) ? Wq : (mat == 1) ? Wk : (mat == 2) ? Wv : Wo;
    unsigned short* dst = (mat < 3) ? WT : WoT;
    int nbase = (mat < 3) ? mat * 1024 : 0;
    int kt = (rem & 31) * 32, nt = (rem >> 5) * 32;
    int tx = tid & 31, ty = tid >> 5;  // 32 x 8
    for (int j = 0; j < 32; j += 8)
        tile[ty + j][tx] = src[(kt + ty + j) * 1024 + nt + tx];
    __syncthreads();
    for (int j = 0; j < 32; j += 8) {
        int n = nt + ty + j;
        dst[(nbase + n) * 1024 + kt + tx] = f2bf(tile[tx][ty + j]);
    }
}

// ---------------------------------------------------------------- GEMM B^T
// C[M,N] = A[M,1024] @ B^T (B stored [N][1024]). 128x128 tile, BK=64.
// Double-buffered gll16 staging (stage t+1 before compute t); XOR swizzle
// (0 bank conflicts). One __syncthreads per K-step; its vmcnt(0) waits only
// the residue of loads issued ~350cy earlier.
// Flat grid + XCD-chunked bijective swizzle.
// Orientation: swapped (C^T) for Q/K columns (n0<2048) and all of EPI1.
template <int EPI, int NBLK>
__global__ __launch_bounds__(256) void gemm_bt(const unsigned short* __restrict__ A,
                                               const unsigned short* __restrict__ B,
                                               unsigned short* __restrict__ Qo,
                                               unsigned short* __restrict__ Ko,
                                               unsigned short* __restrict__ Vo,
                                               const float* __restrict__ bias,
                                               float* __restrict__ Out) {
    __shared__ __align__(16) unsigned short As[2][128 * 64];
    __shared__ __align__(16) unsigned short Bs[2][128 * 64];

    int tid = threadIdx.x;
    int lane = tid & 63, w = tid >> 6;
    int wm = w >> 1, wn = w & 1;
    int lm = lane & 15, quad = lane >> 4;
    // T1 swizzle: bid&7 -> XCD chunk; within chunk m-fastest over the 8-band.
    int bid = blockIdx.x;
    int xcd = bid & 7, ic = bid >> 3;
    int bm = xcd * 8 + (ic & 7), bn = ic >> 3;  // bn in [0, NBLK)
    int m0 = bm * 128, n0 = bn * 128;
    bool sw = (EPI == 1) || (n0 < 2048);  // block-uniform orientation

    // stage one full 128x64 K-tile of A and B into buffer `buf`
    auto STAGE = [&](int buf, int kb) {
#pragma unroll
        for (int p = 0; p < 4; ++p) {
            int id = p * 256 + tid;
            int row = id >> 3;
            int cbs = ((id & 7) ^ (row & 7)) * 8;  // XOR-swizzled source unit
            int lbase = (p * 256 + w * 64) * 8;    // wave-uniform; HW adds lane*16B
            gll16(&A[(m0 + row) * 1024 + kb + cbs], &As[buf][lbase]);
            gll16(&B[(n0 + row) * 1024 + kb + cbs], &Bs[buf][lbase]);
        }
    };

    floatx4 acc[4][4] = {};

    STAGE(0, 0);
    __syncthreads();   // compiler drains vmcnt(0): tile 0 resident

#pragma unroll 2
    for (int t = 0; t < 16; ++t) {
        if (t < 15) STAGE((t + 1) & 1, (t + 1) * 64);  // loads fly under compute
        const unsigned short* Ac = &As[t & 1][0];
        const unsigned short* Bc = &Bs[t & 1][0];

        bf16x8 af[2][4], bf[2][4];
        for (int ks = 0; ks < 2; ++ks)
            for (int i = 0; i < 4; ++i) {
                int pu = (((ks * 4 + quad) ^ (lm & 7))) * 8;  // swizzled unit
                af[ks][i] = *(const bf16x8*)&Ac[(wm * 64 + i * 16 + lm) * 64 + pu];
                bf[ks][i] = *(const bf16x8*)&Bc[(wn * 64 + i * 16 + lm) * 64 + pu];
            }
        if (sw) {
            for (int mi = 0; mi < 4; ++mi)
                for (int ni = 0; ni < 4; ++ni) {
                    acc[mi][ni] = __builtin_amdgcn_mfma_f32_16x16x32_bf16(bf[0][ni], af[0][mi], acc[mi][ni], 0, 0, 0);
                    acc[mi][ni] = __builtin_amdgcn_mfma_f32_16x16x32_bf16(bf[1][ni], af[1][mi], acc[mi][ni], 0, 0, 0);
                }
        } else {
            for (int mi = 0; mi < 4; ++mi)
                for (int ni = 0; ni < 4; ++ni) {
                    acc[mi][ni] = __builtin_amdgcn_mfma_f32_16x16x32_bf16(af[0][mi], bf[0][ni], acc[mi][ni], 0, 0, 0);
                    acc[mi][ni] = __builtin_amdgcn_mfma_f32_16x16x32_bf16(af[1][mi], bf[1][ni], acc[mi][ni], 0, 0, 0);
                }
        }
        // waits lgkmcnt(0) (ds_reads of buf[t&1] done -> safe to restage it
        // next iter) AND vmcnt(0) (buf[(t+1)&1] writes landed -> safe to read).
        __syncthreads();
    }

    if constexpr (EPI == 0) {
        if (sw) {
            // C^T layout: lane owns seq s (col=lm) and 4 consecutive out-cols.
            bool isQ = (n0 < 1024);
            unsigned short* dst = isQ ? Qo : Ko;
            float qs = isQ ? 0.1803368801f : 1.0f;  // 1/8 * log2(e)
            for (int mi = 0; mi < 4; ++mi) {
                int s = m0 + wm * 64 + mi * 16 + lm;
                int bb = s >> 11, sl = s & 2047;
                for (int ni = 0; ni < 4; ++ni) {
                    int gcol0 = n0 + wn * 64 + ni * 16 + quad * 4;
                    int h = (gcol0 & 1023) >> 6, d0 = gcol0 & 63;
                    *(ushort4*)&dst[(((size_t)(bb * 16 + h) * 2048) + sl) * 64 + d0] =
                        pk4(acc[mi][ni][0] * qs, acc[mi][ni][1] * qs,
                            acc[mi][ni][2] * qs, acc[mi][ni][3] * qs);
                }
            }
        } else {
            // V columns, normal layout: packed along seq for V^T [bh][d][2048].
            for (int mi = 0; mi < 4; ++mi) {
                int grow0 = m0 + wm * 64 + mi * 16 + quad * 4;
                int bb = grow0 >> 11, sl = grow0 & 2047;
                for (int ni = 0; ni < 4; ++ni) {
                    int gcol = n0 + wn * 64 + ni * 16 + lm;
                    int hn = gcol & 1023;
                    int h = hn >> 6, d = hn & 63;
                    *(ushort4*)&Vo[((size_t)(bb * 16 + h) * 64 + d) * 2048 + sl] =
                        pk4(acc[mi][ni][0], acc[mi][ni][1], acc[mi][ni][2], acc[mi][ni][3]);
                }
            }
        }
    } else {
        // out-proj: C^T layout -> float4 stores + float4 bias loads
        for (int mi = 0; mi < 4; ++mi) {
            int s = m0 + wm * 64 + mi * 16 + lm;
            for (int ni = 0; ni < 4; ++ni) {
                int gcol0 = n0 + wn * 64 + ni * 16 + quad * 4;
                float4 bv = *(const float4*)&bias[gcol0];
                float4 o;
                o.x = acc[mi][ni][0] + bv.x; o.y = acc[mi][ni][1] + bv.y;
                o.z = acc[mi][ni][2] + bv.z; o.w = acc[mi][ni][3] + bv.w;
                *(float4*)&Out[(size_t)s * 1024 + gcol0] = o;
            }
        }
    }
}

// ------------------------------------------------------------- attention
// Flat grid 1024 = (qt-group g = blk>>6) x 64 bh. 4 blocks/CU co-resident.
// Balanced qt map: qt(g) = {15,13,11,9,8,10,12,14,7,5,3,1,0,2,4,6}[g] so the
// 4 blocks a CU hosts (g, g+4, g+8, g+12) sum to equal work (30 each).
// 512 thr = 8 waves x 16 q-rows. KB=64. S^T orientation: q=lm.
// K lds rows permuted by krho so S^T rows follow
// sigma_n(m)=32(n>>1)+4(n&1)+8(m>>2)+(m&3). PV: window pair (2n1,2n1+1)
// unions to the exact 16x16x32 B-frag (k=8*quad+j) and the b128 V read is
// the matching A-frag -> 8 mfma_16x16x32 per trip, conflict-free LDS.
// setprio(1) around MFMA clusters (T5).
// NO-MAX softmax; Q pre-scaled; lrow reduced once at the end.
__global__ __launch_bounds__(512) void attn(const unsigned short* __restrict__ Q,
                                            const unsigned short* __restrict__ K,
                                            const unsigned short* __restrict__ Vt,
                                            unsigned short* __restrict__ ctx) {
    constexpr int LKS = 72;
    __shared__ __align__(16) unsigned short Ks[2][64 * LKS];
    __shared__ __align__(16) unsigned short Vts[2][64 * LKS];

    int tid = threadIdx.x, lane = tid & 63, w = tid >> 6;   // w: 0..7
    int lm = lane & 15, quad = lane >> 4;
    int blk = blockIdx.x;
    int bh = blk & 63;
    // balanced-resident qt map (branch-free; qtmap is a permutation of 0..15)
    int g = blk >> 6, g2 = g >> 2, r_ = g & 3;
    int qt = 15 - 7 * (g2 & 1) - 8 * (g2 >> 1) + ((g2 & 1) ? 2 * r_ : -2 * r_);
    int trips = 2 * qt + 2;
    int tmax = 2 * qt + (w >> 2);  // last trip this wave computes
    const unsigned short* Qg  = Q  + (size_t)bh * 2048 * 64;
    const unsigned short* Kg  = K  + (size_t)bh * 2048 * 64;
    const unsigned short* Vtg = Vt + (size_t)bh * 64 * 2048;

    int qrow = qt * 128 + w * 16 + lm;
    bf16x8 aq0 = *(const bf16x8*)&Qg[qrow * 64 + quad * 8];
    bf16x8 aq1 = *(const bf16x8*)&Qg[qrow * 64 + 32 + quad * 8];

    floatx4 O[4] = {};            // O^T: per dblk, lane holds d=quad*4+r, q=lm
    float lrow = 0.f;

    int r0 = tid >> 3, c0 = (tid & 7) * 8;  // 512 thr -> rows 0..63, 1 uint4 each
    int rK = krho(r0);                      // permuted K lds row

    {   // prologue: stage tile 0 into buffer 0
        uint4 k0 = *(const uint4*)&Kg[r0 * 64 + c0];
        uint4 v0 = *(const uint4*)&Vtg[r0 * 2048 + c0];
        *(uint4*)&Ks[0][rK * LKS + c0]  = k0;
        *(uint4*)&Vts[0][r0 * LKS + c0] = v0;
    }
    __syncthreads();

    for (int t = 0; t < trips; ++t) {
        int cur = t & 1, nxt = cur ^ 1;
        bool pre = (t + 1 < trips);
        uint4 pk, pv;
        if (pre) {  // issue next tile's loads NOW; they complete under compute
            int kb2 = (t + 1) * 64;
            pk = *(const uint4*)&Kg[(kb2 + r0) * 64 + c0];
            pv = *(const uint4*)&Vtg[r0 * 2048 + kb2 + c0];
        }

        if (t <= tmax) {  // wave-uniform; barriers are outside this branch
            const unsigned short* Kc = Ks[cur];
            const unsigned short* Vc = Vts[cur];

            floatx4 s[4];
            __builtin_amdgcn_s_setprio(1);
            for (int n = 0; n < 4; ++n) {
                bf16x8 a0 = *(const bf16x8*)&Kc[(n * 16 + lm) * LKS + quad * 8];
                bf16x8 a1 = *(const bf16x8*)&Kc[(n * 16 + lm) * LKS + 32 + quad * 8];
                floatx4 z = {};
                z = __builtin_amdgcn_mfma_f32_16x16x32_bf16(a0, aq0, z, 0, 0, 0);
                z = __builtin_amdgcn_mfma_f32_16x16x32_bf16(a1, aq1, z, 0, 0, 0);
                s[n] = z;
            }
            __builtin_amdgcn_s_setprio(0);

            bool diag = (t == tmax);
            if (diag) {
                int qr = (w & 3) * 16 + lm;  // q - kb on this wave's diag tile
                for (int n = 0; n < 4; ++n)
                    for (int r = 0; r < 4; ++r) {
                        int kin = (n >> 1) * 32 + (n & 1) * 4 + quad * 8 + r;
                        if (kin > qr) s[n][r] = -INFINITY;
                    }
            }
            float p[4][4], rs = 0.f;
            for (int n = 0; n < 4; ++n)
                for (int r = 0; r < 4; ++r) {
                    p[n][r] = __builtin_amdgcn_exp2f(s[n][r]);
                    rs += p[n][r];
                }
            lrow += rs;

            // P -> bf16; window pair (2n1,2n1+1) concatenates to the
            // 16x16x32 B-frag: lane holds k = 32n1 + 8*quad + j, j=0..7.
            unsigned int pw[4][2];
            for (int n = 0; n < 4; ++n) {
                pw[n][0] = pkbf(p[n][0], p[n][1]);
                pw[n][1] = pkbf(p[n][2], p[n][3]);
            }
            __builtin_amdgcn_s_setprio(1);
#pragma unroll
            for (int n1 = 0; n1 < 2; ++n1) {
                union { bf16x8 v; unsigned int wd[4]; } pu;
                pu.wd[0] = pw[2 * n1][0];     pu.wd[1] = pw[2 * n1][1];
                pu.wd[2] = pw[2 * n1 + 1][0]; pu.wd[3] = pw[2 * n1 + 1][1];
#pragma unroll
                for (int dblk = 0; dblk < 4; ++dblk) {
                    bf16x8 va = *(const bf16x8*)&Vc[(dblk * 16 + lm) * LKS + n1 * 32 + quad * 8];
                    O[dblk] = __builtin_amdgcn_mfma_f32_16x16x32_bf16(va, pu.v, O[dblk], 0, 0, 0);
                }
            }
            __builtin_amdgcn_s_setprio(0);
        }

        if (pre) {  // loads completed under compute; write into other buffer
            *(uint4*)&Ks[nxt][rK * LKS + c0]  = pk;
            *(uint4*)&Vts[nxt][r0 * LKS + c0] = pv;
        }
        __syncthreads();
    }

    // reduce lrow across the 4 lane-groups holding the same q (once)
    lrow += __shfl_xor(lrow, 16);
    lrow += __shfl_xor(lrow, 32);

    int b = bh >> 4, h = bh & 15;
    int q = qt * 128 + w * 16 + lm;
    float inv = 1.0f / lrow;
    for (int dblk = 0; dblk < 4; ++dblk) {
        *(ushort4*)&ctx[((size_t)(b * 2048 + q)) * 1024 + h * 64 + dblk * 16 + quad * 4] =
            pk4(O[dblk][0] * inv, O[dblk][1] * inv, O[dblk][2] * inv, O[dblk][3] * inv);
    }
}

// ---------------------------------------------------------------- launch
extern "C" void kernel_launch(void* const* d_in, const int* in_sizes, int n_in,
                              void* d_out, int out_size, void* d_ws, size_t ws_size,
                              hipStream_t stream) {
    const float* x   = (const float*)d_in[0];
    const float* Wq  = (const float*)d_in[1];
    const float* Wk  = (const float*)d_in[2];
    const float* Wv  = (const float*)d_in[3];
    const float* Wo  = (const float*)d_in[4];
    const float* bo  = (const float*)d_in[5];
    float* out = (float*)d_out;

    char* ws = (char*)d_ws;
    unsigned short* xb  = (unsigned short*)(ws);               // 16 MB (dead after gemm<0>)
    unsigned short* WT  = (unsigned short*)(ws + 16777216);    // 6 MB
    unsigned short* WoT = (unsigned short*)(ws + 23068672);    // 2 MB
    unsigned short* Qb  = (unsigned short*)(ws + 25165824);    // 16 MB
    unsigned short* Kb  = (unsigned short*)(ws + 41943040);    // 16 MB
    unsigned short* Vtb = (unsigned short*)(ws + 58720256);    // 16 MB (transposed)
    unsigned short* ctx = xb;                                  // alias: xb is dead

    prep<<<12288, 256, 0, stream>>>(x, xb, Wq, Wk, Wv, Wo, WT, WoT);
    gemm_bt<0, 24><<<1536, 256, 0, stream>>>(xb, WT, Qb, Kb, Vtb, nullptr, nullptr);
    attn<<<1024, 512, 0, stream>>>(Qb, Kb, Vtb, ctx);
    gemm_bt<1, 8><<<512, 256, 0, stream>>>(ctx, WoT, nullptr, nullptr, nullptr, bo, out);
}